// Round 1
// baseline (2572.156 us; speedup 1.0000x reference)
//
#include <hip/hip_runtime.h>

#define F1 62400
#define O1 800
#define O2N 100
#define TT 300
#define BB 2
#define BTN (BB*TT)     /* 600 */
#define CAP 4096
#define NSEG 4
#define KSRM 77
#define KREF 11

/* ---- ws layout (bytes) ---- */
#define OFF_CONST 0ull
#define OFF_Z1   1024ull
#define OFF_U1   (OFF_Z1 + 3840000ull)
#define OFF_Z2   (OFF_U1 + 3840000ull)
#define OFF_U2   (OFF_Z2 + 480000ull)
#define OFF_S1   (OFF_U2 + 480000ull)
#define OFF_CNT  (OFF_S1 + 1920000ull)
#define OFF_PART (OFF_CNT + 4096ull)
#define OFF_IDX  (OFF_PART + 15360000ull)
#define OFF_W1T  (OFF_IDX + 9830400ull)
#define NEED_SPARSE (OFF_W1T + 199680000ull)   /* ~224.5 MiB */

/* K0: generate SRM/REF kernels on device, fp64 rounded through fp32 to match
   np.asarray(..., np.float32). eps at c[0..76], ref at c[80..90]. */
__global__ void k0_init(double* c) {
    int k = threadIdx.x;
    if (k < KSRM) {
        double v = ((double)k / 10.0) * exp(1.0 - (double)k / 10.0);
        c[k] = (double)(float)v;
    }
    if (k < KREF) {
        double v = -20.0 * (double)k * exp(1.0 - (double)k);
        c[80 + k] = (double)(float)v;
    }
}

/* K1: build per-(b,t) active-f index lists. One wave handles 64 f's of one b;
   ballot-aggregated atomic append (1 atomic per wave per t). */
__global__ __launch_bounds__(256) void k1_build(const float* __restrict__ x,
                                                int* __restrict__ idx,
                                                int* __restrict__ counts) {
    int gt = blockIdx.x * 256 + threadIdx.x;
    int gw = gt >> 6;
    int lane = threadIdx.x & 63;
    const int nwf = F1 >> 6;           /* 975 waves per b */
    if (gw >= BB * nwf) return;
    int b = gw / nwf, fw = gw % nwf;
    int f = fw * 64 + lane;
    const float* xp = x + ((size_t)b * F1 + f) * TT;
    for (int t = 0; t < TT; ++t) {
        bool on = xp[t] > 0.5f;
        unsigned long long m = __ballot(on);
        if (m == 0ull) continue;
        int cnt = __popcll(m);
        int leader = __builtin_ctzll(m);
        int bt = b * TT + t;
        int base = 0;
        if (lane == leader) base = atomicAdd(&counts[bt], cnt);
        base = __shfl(base, leader, 64);
        if (on) {
            int rank = __popcll(m & ((1ull << lane) - 1ull));
            int pos = base + rank;
            if (pos < CAP) idx[(size_t)bt * CAP + pos] = f;
        }
    }
}

/* K2: transpose w1 (800 x 62400) -> w1t (62400 x 800), 32x32 LDS tiles */
__global__ __launch_bounds__(256) void k2_transpose(const float* __restrict__ w1,
                                                    float* __restrict__ w1t) {
    __shared__ float tile[32][33];
    int fb = blockIdx.x * 32, ob = blockIdx.y * 32;
    int c = threadIdx.x & 31, r0 = threadIdx.x >> 5;
    for (int rr = r0; rr < 32; rr += 8)
        tile[rr][c] = w1[(size_t)(ob + rr) * F1 + fb + c];
    __syncthreads();
    for (int rr = r0; rr < 32; rr += 8)
        w1t[(size_t)(fb + rr) * O1 + ob + c] = tile[c][rr];
}

/* K3: sparse column-sum GEMM1. Block = (bt, seg); 256 threads span o (4 each);
   fp64 register accumulation; writes partials part[bt][seg][o]. */
__global__ __launch_bounds__(256) void k3_spmm(const float* __restrict__ w1t,
                                               const int* __restrict__ idx,
                                               const int* __restrict__ counts,
                                               double* __restrict__ part) {
    int bt = blockIdx.x, seg = blockIdx.y;
    int n = counts[bt];
    if (n > CAP) n = CAP;
    int per = (n + NSEG - 1) / NSEG;
    int i0 = seg * per;
    int i1 = i0 + per; if (i1 > n) i1 = n;
    const int* list = idx + (size_t)bt * CAP;
    int t = threadIdx.x;
    double a0 = 0.0, a1 = 0.0, a2 = 0.0, a3 = 0.0;
    for (int i = i0; i < i1; ++i) {
        int f = __builtin_amdgcn_readfirstlane(list[i]);
        const float* row = w1t + (size_t)f * O1;
        a0 += (double)row[t];
        a1 += (double)row[t + 256];
        a2 += (double)row[t + 512];
        if (t < 32) a3 += (double)row[t + 768];
    }
    double* p = part + ((size_t)bt * NSEG + seg) * O1;
    p[t] = a0; p[t + 256] = a1; p[t + 512] = a2;
    if (t < 32) p[t + 768] = a3;
}

/* K4: reduce partials -> z1 in (b*800+o, t) layout, fp64 */
__global__ __launch_bounds__(320) void k4_reduce(const double* __restrict__ part,
                                                 double* __restrict__ z1) {
    int row = blockIdx.x;               /* b*800+o */
    int t = threadIdx.x; if (t >= TT) return;
    int b = row / O1, o = row % O1;
    int bt = b * TT + t;
    double s = 0.0;
    #pragma unroll
    for (int g = 0; g < NSEG; ++g) s += part[((size_t)bt * NSEG + g) * O1 + o];
    z1[(size_t)row * TT + t] = s;
}

/* dense fallback GEMM1 (used only if ws too small): fp32 64-chunk inner,
   fp64 chunk accumulation */
__global__ __launch_bounds__(256) void k_dense_gemm1(const float* __restrict__ x,
                                                     const float* __restrict__ w1,
                                                     double* __restrict__ z1) {
    int lin = blockIdx.x;
    int ot = lin % 25; int tt = (lin / 25) % 5; int b = lin / 125;
    int t0 = tt * 64, o0 = ot * 32;
    __shared__ float xs[64][64];
    __shared__ float wsh[32][64];
    int ti = threadIdx.x & 63, og = threadIdx.x >> 6;
    double dacc[8] = {0, 0, 0, 0, 0, 0, 0, 0};
    for (int fc = 0; fc < F1; fc += 64) {
        __syncthreads();
        for (int e = threadIdx.x; e < 64 * 64; e += 256) {
            int r = e >> 6, c = e & 63;
            int t = t0 + c;
            xs[r][c] = (t < TT) ? x[((size_t)b * F1 + fc + r) * TT + t] : 0.0f;
        }
        for (int e = threadIdx.x; e < 32 * 64; e += 256) {
            int r = e >> 6, c = e & 63;
            wsh[r][c] = w1[(size_t)(o0 + r) * F1 + fc + c];
        }
        __syncthreads();
        float facc[8] = {0, 0, 0, 0, 0, 0, 0, 0};
        for (int ff = 0; ff < 64; ++ff) {
            float xv = xs[ff][ti];
            #pragma unroll
            for (int oo = 0; oo < 8; ++oo) facc[oo] += wsh[og * 8 + oo][ff] * xv;
        }
        #pragma unroll
        for (int oo = 0; oo < 8; ++oo) dacc[oo] += (double)facc[oo];
    }
    int t = t0 + ti;
    if (t < TT) {
        #pragma unroll
        for (int oo = 0; oo < 8; ++oo) {
            int o = o0 + og * 8 + oo;
            z1[((size_t)(b * O1 + o)) * TT + t] = dacc[oo];
        }
    }
}

/* K5: causal SRM-alpha conv (psp), fp64. grid = rows, threads = t */
__global__ __launch_bounds__(320) void k5_psp(const double* __restrict__ z,
                                              double* __restrict__ u,
                                              const double* __restrict__ cst) {
    int row = blockIdx.x;
    int t = threadIdx.x; if (t >= TT) return;
    const double* zr = z + (size_t)row * TT;
    int kmax = t < (KSRM - 1) ? t : (KSRM - 1);
    double acc = 0.0;
    for (int k = 0; k <= kmax; ++k) acc += cst[k] * zr[t - k];
    u[(size_t)row * TT + t] = acc;
}

/* K6: spike scan layer 1 -> s1 in (b,t,f) layout (f32, binary) */
__global__ __launch_bounds__(64) void k6_spike1(const double* __restrict__ u,
                                                float* __restrict__ s_out,
                                                const double* __restrict__ cst) {
    int row = blockIdx.x * 64 + threadIdx.x;
    if (row >= BB * O1) return;
    int b = row / O1, o = row % O1;
    double rk[KREF];
    #pragma unroll
    for (int d = 0; d < KREF; ++d) rk[d] = cst[80 + d];
    const double* ur = u + (size_t)row * TT;
    unsigned hist = 0;                 /* bit (d-1): spike at t-d */
    for (int t = 0; t < TT; ++t) {
        double ueff = ur[t];
        #pragma unroll
        for (int d = 1; d < KREF; ++d)
            if (hist & (1u << (d - 1))) ueff += rk[d];
        int sp = (ueff >= 10.0) ? 1 : 0;
        s_out[((size_t)(b * TT + t)) * O1 + o] = (float)sp;
        hist = (hist << 1) | (unsigned)sp;
    }
}

/* K7: GEMM2, fp64 acc. block = (b*100+o2); threads = t */
__global__ __launch_bounds__(320) void k7_gemm2(const float* __restrict__ s1,
                                                const float* __restrict__ w2,
                                                double* __restrict__ z2) {
    int bo = blockIdx.x;
    int t = threadIdx.x; if (t >= TT) return;
    int b = bo / O2N, o2 = bo % O2N;
    const float* srow = s1 + ((size_t)(b * TT + t)) * O1;
    const float* wrow = w2 + (size_t)o2 * O1;
    double acc = 0.0;
    for (int f = 0; f < O1; ++f) acc += (double)(wrow[f] * srow[f]);
    z2[(size_t)bo * TT + t] = acc;
}

/* K9: spike scan layer 2 -> output (b,o2,t) fp32 */
__global__ __launch_bounds__(64) void k9_spike2(const double* __restrict__ u,
                                                float* __restrict__ out,
                                                const double* __restrict__ cst) {
    int row = blockIdx.x * 64 + threadIdx.x;
    if (row >= BB * O2N) return;
    double rk[KREF];
    #pragma unroll
    for (int d = 0; d < KREF; ++d) rk[d] = cst[80 + d];
    const double* ur = u + (size_t)row * TT;
    unsigned hist = 0;
    for (int t = 0; t < TT; ++t) {
        double ueff = ur[t];
        #pragma unroll
        for (int d = 1; d < KREF; ++d)
            if (hist & (1u << (d - 1))) ueff += rk[d];
        int sp = (ueff >= 10.0) ? 1 : 0;
        out[(size_t)row * TT + t] = (float)sp;
        hist = (hist << 1) | (unsigned)sp;
    }
}

extern "C" void kernel_launch(void* const* d_in, const int* in_sizes, int n_in,
                              void* d_out, int out_size, void* d_ws, size_t ws_size,
                              hipStream_t stream) {
    const float* x  = (const float*)d_in[0];
    const float* w1 = (const float*)d_in[1];
    const float* w2 = (const float*)d_in[2];
    float* out = (float*)d_out;
    char* ws = (char*)d_ws;

    double* cst  = (double*)(ws + OFF_CONST);
    double* z1   = (double*)(ws + OFF_Z1);
    double* u1   = (double*)(ws + OFF_U1);
    double* z2   = (double*)(ws + OFF_Z2);
    double* u2   = (double*)(ws + OFF_U2);
    float*  s1   = (float*) (ws + OFF_S1);
    int*    cnts = (int*)   (ws + OFF_CNT);
    double* part = (double*)(ws + OFF_PART);
    int*    idx  = (int*)   (ws + OFF_IDX);
    float*  w1t  = (float*) (ws + OFF_W1T);

    k0_init<<<1, 128, 0, stream>>>(cst);

    if (ws_size >= NEED_SPARSE) {
        hipMemsetAsync(cnts, 0, BTN * sizeof(int), stream);
        {   /* K1: 2*975 waves = 124800 threads */
            int blocks = (BB * (F1 >> 6) * 64 + 255) / 256;
            k1_build<<<blocks, 256, 0, stream>>>(x, idx, cnts);
        }
        k2_transpose<<<dim3(F1 / 32, O1 / 32), 256, 0, stream>>>(w1, w1t);
        k3_spmm<<<dim3(BTN, NSEG), 256, 0, stream>>>(w1t, idx, cnts, part);
        k4_reduce<<<BB * O1, 320, 0, stream>>>(part, z1);
    } else {
        k_dense_gemm1<<<250, 256, 0, stream>>>(x, w1, z1);
    }

    k5_psp<<<BB * O1, 320, 0, stream>>>(z1, u1, cst);
    k6_spike1<<<(BB * O1 + 63) / 64, 64, 0, stream>>>(u1, s1, cst);
    k7_gemm2<<<BB * O2N, 320, 0, stream>>>(s1, w2, z2);
    k5_psp<<<BB * O2N, 320, 0, stream>>>(z2, u2, cst);
    k9_spike2<<<(BB * O2N + 63) / 64, 64, 0, stream>>>(u2, out, cst);
    (void)in_sizes; (void)n_in; (void)out_size;
}

// Round 2
// 1175.103 us; speedup vs baseline: 2.1889x; 2.1889x over previous
//
#include <hip/hip_runtime.h>

#define F1 62400
#define O1 800
#define O2N 100
#define TT 300
#define BB 2
#define BTN (BB*TT)     /* 600 */
#define NW  975         /* F1/64 words per (b,t) bitmask */
#define NSEG 4
#define KSRM 77
#define KREF 11

/* ---- ws layout (bytes) ---- */
#define OFF_CONST 0ull
#define OFF_Z1   1024ull
#define OFF_U1   (OFF_Z1 + 3840000ull)
#define OFF_Z2   (OFF_U1 + 3840000ull)
#define OFF_U2   (OFF_Z2 + 480000ull)
#define OFF_S1   (OFF_U2 + 480000ull)
#define OFF_XB   (OFF_S1 + 1920000ull)
#define OFF_PART (OFF_XB + 4680000ull)     /* xb: 600*975*8 */
#define OFF_W1T  (OFF_PART + 15360000ull)
#define NEED_SPARSE (OFF_W1T + 199680000ull)   /* ~219.6 MiB (< R1's 224.5 MiB which fit) */

/* K0: generate SRM/REF kernels on device, fp64 rounded through fp32 to match
   np.asarray(..., np.float32). eps at c[0..76], ref at c[80..90]. */
__global__ void k0_init(double* c) {
    int k = threadIdx.x;
    if (k < KSRM) {
        double v = ((double)k / 10.0) * exp(1.0 - (double)k / 10.0);
        c[k] = (double)(float)v;
    }
    if (k < KREF) {
        double v = -20.0 * (double)k * exp(1.0 - (double)k);
        c[80 + k] = (double)(float)v;
    }
}

/* K1: build bitmask xb[bt][w]: bit j of word w = (x[b][w*64+j][t] > 0.5).
   Wave = (b, f-word fw, t-group). lane = t offset -> fully coalesced loads,
   no atomics, no cross-lane ops. */
__global__ __launch_bounds__(256) void k1_bitmask(const float* __restrict__ x,
                                                  unsigned long long* __restrict__ xb) {
    const int NTG = 5;                               /* ceil(300/64) */
    int gw = (blockIdx.x * 256 + threadIdx.x) >> 6;
    int lane = threadIdx.x & 63;
    if (gw >= BB * NW * NTG) return;
    int b  = gw / (NW * NTG);
    int r  = gw % (NW * NTG);
    int fw = r / NTG;
    int tg = r % NTG;
    int t = tg * 64 + lane;
    bool act = (t < TT);
    int tc = act ? t : 0;
    const float* xp = x + ((size_t)(b * F1 + (fw << 6))) * TT + tc;
    unsigned lo = 0, hi = 0;
    #pragma unroll
    for (int j = 0; j < 32; ++j)
        lo |= (xp[(size_t)j * TT] > 0.5f ? 1u : 0u) << j;
    #pragma unroll
    for (int j = 0; j < 32; ++j)
        hi |= (xp[(size_t)(j + 32) * TT] > 0.5f ? 1u : 0u) << j;
    if (act)
        xb[(size_t)(b * TT + t) * NW + fw] = ((unsigned long long)hi << 32) | lo;
}

/* K2: transpose w1 (800 x 62400) -> w1t (62400 x 800), 32x32 LDS tiles */
__global__ __launch_bounds__(256) void k2_transpose(const float* __restrict__ w1,
                                                    float* __restrict__ w1t) {
    __shared__ float tile[32][33];
    int fb = blockIdx.x * 32, ob = blockIdx.y * 32;
    int c = threadIdx.x & 31, r0 = threadIdx.x >> 5;
    for (int rr = r0; rr < 32; rr += 8)
        tile[rr][c] = w1[(size_t)(ob + rr) * F1 + fb + c];
    __syncthreads();
    for (int rr = r0; rr < 32; rr += 8)
        w1t[(size_t)(fb + rr) * O1 + ob + c] = tile[c][rr];
}

/* K3: sparse column-sum GEMM1 from the bitmask. Block = (bt, seg); 256
   threads span o (up to 4 each); fp64 register accumulation. */
__global__ __launch_bounds__(256) void k3_spmm(const float* __restrict__ w1t,
                                               const unsigned long long* __restrict__ xb,
                                               double* __restrict__ part) {
    const int WPS = (NW + NSEG - 1) / NSEG;          /* 244 */
    int bt = blockIdx.x, seg = blockIdx.y;
    int w0 = seg * WPS;
    int w1e = w0 + WPS; if (w1e > NW) w1e = NW;
    const unsigned long long* wp = xb + (size_t)bt * NW;
    int t = threadIdx.x;
    double a0 = 0.0, a1 = 0.0, a2 = 0.0, a3 = 0.0;
    for (int w = w0; w < w1e; ++w) {
        unsigned long long mv = wp[w];
        unsigned mlo = __builtin_amdgcn_readfirstlane((unsigned)mv);
        unsigned mhi = __builtin_amdgcn_readfirstlane((unsigned)(mv >> 32));
        unsigned long long m = ((unsigned long long)mhi << 32) | mlo;
        while (m) {
            int f = (w << 6) + __builtin_ctzll(m);
            m &= m - 1;
            const float* row = w1t + (size_t)f * O1;
            a0 += (double)row[t];
            a1 += (double)row[t + 256];
            a2 += (double)row[t + 512];
            if (t < 32) a3 += (double)row[t + 768];
        }
    }
    double* p = part + ((size_t)bt * NSEG + seg) * O1;
    p[t] = a0; p[t + 256] = a1; p[t + 512] = a2;
    if (t < 32) p[t + 768] = a3;
}

/* K4: reduce partials -> z1 in (b*800+o, t) layout, fp64 */
__global__ __launch_bounds__(320) void k4_reduce(const double* __restrict__ part,
                                                 double* __restrict__ z1) {
    int row = blockIdx.x;               /* b*800+o */
    int t = threadIdx.x; if (t >= TT) return;
    int b = row / O1, o = row % O1;
    int bt = b * TT + t;
    double s = 0.0;
    #pragma unroll
    for (int g = 0; g < NSEG; ++g) s += part[((size_t)bt * NSEG + g) * O1 + o];
    z1[(size_t)row * TT + t] = s;
}

/* dense fallback GEMM1 (used only if ws too small) */
__global__ __launch_bounds__(256) void k_dense_gemm1(const float* __restrict__ x,
                                                     const float* __restrict__ w1,
                                                     double* __restrict__ z1) {
    int lin = blockIdx.x;
    int ot = lin % 25; int tt = (lin / 25) % 5; int b = lin / 125;
    int t0 = tt * 64, o0 = ot * 32;
    __shared__ float xs[64][64];
    __shared__ float wsh[32][64];
    int ti = threadIdx.x & 63, og = threadIdx.x >> 6;
    double dacc[8] = {0, 0, 0, 0, 0, 0, 0, 0};
    for (int fc = 0; fc < F1; fc += 64) {
        __syncthreads();
        for (int e = threadIdx.x; e < 64 * 64; e += 256) {
            int r = e >> 6, c = e & 63;
            int t = t0 + c;
            xs[r][c] = (t < TT) ? x[((size_t)b * F1 + fc + r) * TT + t] : 0.0f;
        }
        for (int e = threadIdx.x; e < 32 * 64; e += 256) {
            int r = e >> 6, c = e & 63;
            wsh[r][c] = w1[(size_t)(o0 + r) * F1 + fc + c];
        }
        __syncthreads();
        float facc[8] = {0, 0, 0, 0, 0, 0, 0, 0};
        for (int ff = 0; ff < 64; ++ff) {
            float xv = xs[ff][ti];
            #pragma unroll
            for (int oo = 0; oo < 8; ++oo) facc[oo] += wsh[og * 8 + oo][ff] * xv;
        }
        #pragma unroll
        for (int oo = 0; oo < 8; ++oo) dacc[oo] += (double)facc[oo];
    }
    int t = t0 + ti;
    if (t < TT) {
        #pragma unroll
        for (int oo = 0; oo < 8; ++oo) {
            int o = o0 + og * 8 + oo;
            z1[((size_t)(b * O1 + o)) * TT + t] = dacc[oo];
        }
    }
}

/* K5: causal SRM-alpha conv (psp), fp64. grid = rows, threads = t */
__global__ __launch_bounds__(320) void k5_psp(const double* __restrict__ z,
                                              double* __restrict__ u,
                                              const double* __restrict__ cst) {
    int row = blockIdx.x;
    int t = threadIdx.x; if (t >= TT) return;
    const double* zr = z + (size_t)row * TT;
    int kmax = t < (KSRM - 1) ? t : (KSRM - 1);
    double acc = 0.0;
    for (int k = 0; k <= kmax; ++k) acc += cst[k] * zr[t - k];
    u[(size_t)row * TT + t] = acc;
}

/* K6: spike scan layer 1 -> s1 in (b,t,f) layout (f32, binary) */
__global__ __launch_bounds__(64) void k6_spike1(const double* __restrict__ u,
                                                float* __restrict__ s_out,
                                                const double* __restrict__ cst) {
    int row = blockIdx.x * 64 + threadIdx.x;
    if (row >= BB * O1) return;
    int b = row / O1, o = row % O1;
    double rk[KREF];
    #pragma unroll
    for (int d = 0; d < KREF; ++d) rk[d] = cst[80 + d];
    const double* ur = u + (size_t)row * TT;
    unsigned hist = 0;                 /* bit (d-1): spike at t-d */
    for (int t = 0; t < TT; ++t) {
        double ueff = ur[t];
        #pragma unroll
        for (int d = 1; d < KREF; ++d)
            if (hist & (1u << (d - 1))) ueff += rk[d];
        int sp = (ueff >= 10.0) ? 1 : 0;
        s_out[((size_t)(b * TT + t)) * O1 + o] = (float)sp;
        hist = (hist << 1) | (unsigned)sp;
    }
}

/* K7: GEMM2, fp64 acc. block = (b*100+o2); threads = t */
__global__ __launch_bounds__(320) void k7_gemm2(const float* __restrict__ s1,
                                                const float* __restrict__ w2,
                                                double* __restrict__ z2) {
    int bo = blockIdx.x;
    int t = threadIdx.x; if (t >= TT) return;
    int b = bo / O2N, o2 = bo % O2N;
    const float* srow = s1 + ((size_t)(b * TT + t)) * O1;
    const float* wrow = w2 + (size_t)o2 * O1;
    double acc = 0.0;
    for (int f = 0; f < O1; ++f) acc += (double)(wrow[f] * srow[f]);
    z2[(size_t)bo * TT + t] = acc;
}

/* K9: spike scan layer 2 -> output (b,o2,t) fp32 */
__global__ __launch_bounds__(64) void k9_spike2(const double* __restrict__ u,
                                                float* __restrict__ out,
                                                const double* __restrict__ cst) {
    int row = blockIdx.x * 64 + threadIdx.x;
    if (row >= BB * O2N) return;
    double rk[KREF];
    #pragma unroll
    for (int d = 0; d < KREF; ++d) rk[d] = cst[80 + d];
    const double* ur = u + (size_t)row * TT;
    unsigned hist = 0;
    for (int t = 0; t < TT; ++t) {
        double ueff = ur[t];
        #pragma unroll
        for (int d = 1; d < KREF; ++d)
            if (hist & (1u << (d - 1))) ueff += rk[d];
        int sp = (ueff >= 10.0) ? 1 : 0;
        out[(size_t)row * TT + t] = (float)sp;
        hist = (hist << 1) | (unsigned)sp;
    }
}

extern "C" void kernel_launch(void* const* d_in, const int* in_sizes, int n_in,
                              void* d_out, int out_size, void* d_ws, size_t ws_size,
                              hipStream_t stream) {
    const float* x  = (const float*)d_in[0];
    const float* w1 = (const float*)d_in[1];
    const float* w2 = (const float*)d_in[2];
    float* out = (float*)d_out;
    char* ws = (char*)d_ws;

    double* cst  = (double*)(ws + OFF_CONST);
    double* z1   = (double*)(ws + OFF_Z1);
    double* u1   = (double*)(ws + OFF_U1);
    double* z2   = (double*)(ws + OFF_Z2);
    double* u2   = (double*)(ws + OFF_U2);
    float*  s1   = (float*) (ws + OFF_S1);
    unsigned long long* xb = (unsigned long long*)(ws + OFF_XB);
    double* part = (double*)(ws + OFF_PART);
    float*  w1t  = (float*) (ws + OFF_W1T);

    k0_init<<<1, 128, 0, stream>>>(cst);

    if (ws_size >= NEED_SPARSE) {
        const int NTG = 5;
        int blocks = (BB * NW * NTG * 64 + 255) / 256;   /* 2438 */
        k1_bitmask<<<blocks, 256, 0, stream>>>(x, xb);
        k2_transpose<<<dim3(F1 / 32, O1 / 32), 256, 0, stream>>>(w1, w1t);
        k3_spmm<<<dim3(BTN, NSEG), 256, 0, stream>>>(w1t, xb, part);
        k4_reduce<<<BB * O1, 320, 0, stream>>>(part, z1);
    } else {
        k_dense_gemm1<<<250, 256, 0, stream>>>(x, w1, z1);
    }

    k5_psp<<<BB * O1, 320, 0, stream>>>(z1, u1, cst);
    k6_spike1<<<(BB * O1 + 63) / 64, 64, 0, stream>>>(u1, s1, cst);
    k7_gemm2<<<BB * O2N, 320, 0, stream>>>(s1, w2, z2);
    k5_psp<<<BB * O2N, 320, 0, stream>>>(z2, u2, cst);
    k9_spike2<<<(BB * O2N + 63) / 64, 64, 0, stream>>>(u2, out, cst);
    (void)in_sizes; (void)n_in; (void)out_size;
}